// Round 2
// 707.424 us; speedup vs baseline: 1.2123x; 1.2123x over previous
//
#include <hip/hip_runtime.h>
#include <hip/hip_bf16.h>
#include <stdint.h>

#define N_NODES 50000
#define N_EDGES 1600000
#define D_FEAT  512
#define UNITS   512

typedef __attribute__((ext_vector_type(8))) unsigned short u16x8;
typedef __attribute__((ext_vector_type(8))) short s16x8;
typedef __attribute__((ext_vector_type(4))) float f32x4;

static __device__ __forceinline__ float bfr(unsigned short u) {
    union { unsigned int i; float f; } c;
    c.i = ((unsigned int)u) << 16;
    return c.f;
}

static __device__ __forceinline__ unsigned short f2bfr(float f) {
    union { unsigned int i; float f; } c;
    c.f = f;
    unsigned int x = c.i;
    unsigned int rounded = x + 0x7FFF + ((x >> 16) & 1);
    return (unsigned short)(rounded >> 16);
}

// async 16B global -> LDS (width=16 verified on gfx950)
static __device__ __forceinline__ void gload16(const unsigned short* g, unsigned short* l) {
    __builtin_amdgcn_global_load_lds(
        (const __attribute__((address_space(1))) void*)g,
        (__attribute__((address_space(3))) void*)l, 16, 0, 0);
}

// flags: [0]=X bf16, [1]=W bf16, [2]=bias bf16, [3]=ew bf16, [4]=esrc int64, [5]=edst int64
extern "C" __global__ void __launch_bounds__(64) GCN_detect(
    const void* X, const void* W, const void* bias, const void* ew,
    const void* esrc, const void* edst, int* flags)
{
    int t = threadIdx.x;
    const unsigned short uX = ((const unsigned short*)X)[2 * t];
    const unsigned short uW = ((const unsigned short*)W)[2 * t];
    const unsigned short uB = ((const unsigned short*)bias)[2 * t];
    const unsigned short uE = ((const unsigned short*)ew)[2 * t];
    int eX = (uX >> 7) & 0xFF, eW = (uW >> 7) & 0xFF;
    int eB = (uB >> 7) & 0xFF, eE = (uE >> 7) & 0xFF;
    unsigned long long mX = __ballot((uX == 0) || (eX >= 100 && eX <= 140));
    unsigned long long mW = __ballot((uW == 0) || (eW >= 100 && eW <= 140));
    unsigned long long mB = __ballot((uB == 0) || (eB >= 100 && eB <= 140));
    unsigned long long mE = __ballot((uE == 0) || (eE >= 100 && eE <= 140));
    unsigned long long mS = __ballot(((const int*)esrc)[2 * t + 1] == 0);
    unsigned long long mD = __ballot(((const int*)edst)[2 * t + 1] == 0);
    if (t == 0) {
        flags[0] = (__popcll(mX) >= 56) ? 1 : 0;
        flags[1] = (__popcll(mW) >= 56) ? 1 : 0;
        flags[2] = (__popcll(mB) >= 56) ? 1 : 0;
        flags[3] = (__popcll(mE) >= 56) ? 1 : 0;
        flags[4] = (__popcll(mS) >= 56) ? 1 : 0;
        flags[5] = (__popcll(mD) >= 56) ? 1 : 0;
    }
}

// ---------------- zero per-dst counts
extern "C" __global__ void __launch_bounds__(256) GCN_zero(int* __restrict__ counts)
{
    int i = blockIdx.x * 256 + threadIdx.x;
    if (i < N_NODES) counts[i] = 0;
}

// ---------------- convert X -> bf16 (only runs work when X is fp32)
extern "C" __global__ void __launch_bounds__(256) GCN_xconv(
    const void* __restrict__ Xp, unsigned short* __restrict__ Xb,
    const int* __restrict__ flags)
{
    if (flags[0]) return; // already bf16, GEMM reads X directly
    const float4* Xf = (const float4*)Xp;
    const long long NQ = (long long)N_NODES * D_FEAT / 4;
    long long stride = (long long)gridDim.x * 256;
    for (long long q = (long long)blockIdx.x * 256 + threadIdx.x; q < NQ; q += stride) {
        float4 v = Xf[q];
        ushort4 o;
        o.x = f2bfr(v.x); o.y = f2bfr(v.y); o.z = f2bfr(v.z); o.w = f2bfr(v.w);
        *(ushort4*)(Xb + q * 4) = o;
    }
}

// ---------------- Wt[n][k] = bf16(W[k][n])  (512x512, LDS tile transpose)
extern "C" __global__ void __launch_bounds__(256) GCN_wt(
    const void* __restrict__ Wp, unsigned short* __restrict__ Wt,
    const int* __restrict__ flags)
{
    __shared__ unsigned short tile[64][65];
    const int wbf = flags[1];
    int k0 = blockIdx.x * 64, n0 = blockIdx.y * 64;
    int t = threadIdx.x;
    for (int p = 0; p < 16; p++) {
        int idx = p * 256 + t;
        int r = idx >> 6, c = idx & 63;
        unsigned short v;
        if (wbf) {
            v = ((const unsigned short*)Wp)[(long long)(k0 + r) * UNITS + n0 + c];
        } else {
            v = f2bfr(((const float*)Wp)[(long long)(k0 + r) * UNITS + n0 + c]);
        }
        tile[r][c] = v;
    }
    __syncthreads();
    for (int p = 0; p < 16; p++) {
        int idx = p * 256 + t;
        int r = idx >> 6, c = idx & 63;
        Wt[(long long)(n0 + r) * D_FEAT + k0 + c] = tile[c][r];
    }
}

// ---------------- histogram of dst
extern "C" __global__ void __launch_bounds__(256) GCN_hist(
    const void* __restrict__ edstp, int* __restrict__ counts,
    const int* __restrict__ flags)
{
    const int d64 = flags[5];
    int e = blockIdx.x * 256 + threadIdx.x;
    if (e >= N_EDGES) return;
    int dst;
    if (d64) {
        dst = (int)((const long long*)edstp)[e];
    } else {
        dst = ((const int*)edstp)[e];
    }
    atomicAdd(&counts[dst], 1);
}

// ---------------- 3-phase exclusive prefix sum (replaces serial 1-block scan)
// scan1: per-block (256-wide) exclusive scan -> row_ptr (chunk-local), block sums
extern "C" __global__ void __launch_bounds__(256) GCN_scan1(
    const int* __restrict__ counts, int* __restrict__ row_ptr,
    int* __restrict__ blk_sums)
{
    __shared__ int ws[4];
    int b = blockIdx.x, tid = threadIdx.x;
    int idx = b * 256 + tid;
    int v = (idx < N_NODES) ? counts[idx] : 0;
    int lane = tid & 63, wv = tid >> 6;
    int x = v;
    #pragma unroll
    for (int off = 1; off < 64; off <<= 1) {
        int y = __shfl_up(x, off, 64);
        if (lane >= off) x += y;
    }
    if (lane == 63) ws[wv] = x;
    __syncthreads();
    int wo = 0;
    for (int w = 0; w < wv; w++) wo += ws[w];
    int incl = x + wo;
    if (idx < N_NODES) row_ptr[idx] = incl - v;  // exclusive, chunk-local
    if (tid == 255) blk_sums[b] = incl;
}

// scan2: single block scans the 196 block sums -> block offsets + total
extern "C" __global__ void __launch_bounds__(256) GCN_scan2(
    const int* __restrict__ blk_sums, int* __restrict__ blk_offs,
    int* __restrict__ row_ptr)
{
    __shared__ int ws[4];
    const int NB = (N_NODES + 255) / 256;  // 196
    int tid = threadIdx.x;
    int v = (tid < NB) ? blk_sums[tid] : 0;
    int lane = tid & 63, wv = tid >> 6;
    int x = v;
    #pragma unroll
    for (int off = 1; off < 64; off <<= 1) {
        int y = __shfl_up(x, off, 64);
        if (lane >= off) x += y;
    }
    if (lane == 63) ws[wv] = x;
    __syncthreads();
    int wo = 0;
    for (int w = 0; w < wv; w++) wo += ws[w];
    int incl = x + wo;
    if (tid < NB) blk_offs[tid] = incl - v;
    if (tid == 255) row_ptr[N_NODES] = incl;  // total edges
}

// scan3: add block offsets, fill row_fill
extern "C" __global__ void __launch_bounds__(256) GCN_scan3(
    int* __restrict__ row_ptr, int* __restrict__ row_fill,
    const int* __restrict__ blk_offs)
{
    int idx = blockIdx.x * 256 + threadIdx.x;
    if (idx < N_NODES) {
        int v = row_ptr[idx] + blk_offs[blockIdx.x];
        row_ptr[idx] = v;
        row_fill[idx] = v;
    }
}

// ---------------- build CSR (src packed as u16: N_NODES < 65536)
extern "C" __global__ void __launch_bounds__(256) GCN_build(
    const void* __restrict__ esrcp, const void* __restrict__ edstp,
    const void* __restrict__ ewp, int* __restrict__ row_fill,
    unsigned short* __restrict__ csr_src, float* __restrict__ csr_w,
    const int* __restrict__ flags)
{
    const int ewbf = flags[3];
    const int s64 = flags[4];
    const int d64 = flags[5];
    int e = blockIdx.x * 256 + threadIdx.x;
    if (e >= N_EDGES) return;
    int src, dst;
    if (s64) {
        src = (int)((const long long*)esrcp)[e];
    } else {
        src = ((const int*)esrcp)[e];
    }
    if (d64) {
        dst = (int)((const long long*)edstp)[e];
    } else {
        dst = ((const int*)edstp)[e];
    }
    float w;
    if (ewbf) {
        w = bfr(((const unsigned short*)ewp)[e]);
    } else {
        w = ((const float*)ewp)[e];
    }
    int pos = atomicAdd(&row_fill[dst], 1);
    csr_src[pos] = (unsigned short)src;
    csr_w[pos] = w;
}

// ---------------- MFMA GEMM: h[M,N] = X[M,K] @ W[K,N], m97 structure
// 128x128 tile, BK=32, 4 waves (2x2), each wave 4x4 of 16x16x32 bf16 MFMA.
extern "C" __global__ void __launch_bounds__(256) GCN_gemm_mfma(
    const void* __restrict__ Xp, const unsigned short* __restrict__ Xb,
    const unsigned short* __restrict__ Wt,
    unsigned short* __restrict__ Cu, const int* __restrict__ flags)
{
    __shared__ unsigned short As[128 * 32];  // 8 KB, row-major [m][k]
    __shared__ unsigned short Bs[128 * 32];  // 8 KB, row-major [n][k]

    const unsigned short* Xsrc = flags[0] ? (const unsigned short*)Xp : Xb;

    const int tid  = threadIdx.x;
    const int wave = tid >> 6, lane = tid & 63;
    const int quad = lane >> 4, l16 = lane & 15;
    const int wm = wave >> 1, wn = wave & 1;
    const int row0 = blockIdx.y * 128;   // M tile
    const int n0   = blockIdx.x * 128;   // N tile

    f32x4 acc[4][4];
    #pragma unroll
    for (int i = 0; i < 4; i++) {
        #pragma unroll
        for (int j = 0; j < 4; j++) {
            acc[i][j] = (f32x4){0.0f, 0.0f, 0.0f, 0.0f};
        }
    }

    for (int k0 = 0; k0 < D_FEAT; k0 += 32) {
        // stage A (128x32) and B (128x32): 512 x 16B each, 256 threads x 2
        #pragma unroll
        for (int it = 0; it < 2; it++) {
            int flat = it * 256 + tid;          // 0..511
            int r = flat >> 2, cb = flat & 3;   // row, 8-elem chunk
            int gr = row0 + r;
            if (gr > N_NODES - 1) gr = N_NODES - 1;   // clamp (dup loads ok)
            gload16(Xsrc + (long long)gr * D_FEAT + k0 + cb * 8, As + flat * 8);
            gload16(Wt + (long long)(n0 + r) * D_FEAT + k0 + cb * 8, Bs + flat * 8);
        }
        __syncthreads();

        s16x8 a[4], b[4];
        #pragma unroll
        for (int i = 0; i < 4; i++) {
            a[i] = *(const s16x8*)(As + ((wm * 64 + i * 16 + l16) * 32 + quad * 8));
        }
        #pragma unroll
        for (int j = 0; j < 4; j++) {
            b[j] = *(const s16x8*)(Bs + ((wn * 64 + j * 16 + l16) * 32 + quad * 8));
        }
        #pragma unroll
        for (int i = 0; i < 4; i++) {
            #pragma unroll
            for (int j = 0; j < 4; j++) {
                acc[i][j] = __builtin_amdgcn_mfma_f32_16x16x32_bf16(
                    a[i], b[j], acc[i][j], 0, 0, 0);
            }
        }
        __syncthreads();
    }

    // epilogue: C/D layout col=lane&15, row=quad*4+reg (m89-verified)
    #pragma unroll
    for (int i = 0; i < 4; i++) {
        #pragma unroll
        for (int r = 0; r < 4; r++) {
            int gr = row0 + wm * 64 + i * 16 + quad * 4 + r;
            if (gr < N_NODES) {
                #pragma unroll
                for (int j = 0; j < 4; j++) {
                    int gc = n0 + wn * 64 + j * 16 + l16;
                    Cu[(long long)gr * UNITS + gc] = f2bfr(acc[i][j][r]);
                }
            }
        }
    }
}

// ---------------- Aggregate: column-sliced (64 units/slice), XCD-pinned slices.
// 8 slices x 256 chunks = 2048 blocks; slice = blockIdx.x & 7 -> XCD (round-robin).
// Per-XCD L2 then holds one 6.4 MB h slice; gathers become L2-resident.
// Wave = 8 edge-groups x 8 column-lanes; xor-shuffle reduce across groups.
extern "C" __global__ void __launch_bounds__(256) GCNConv_86311662780630_kernel(
    const unsigned short* __restrict__ h,
    const int* __restrict__ row_ptr,
    const unsigned short* __restrict__ csr_src,
    const float* __restrict__ csr_w,
    const void* __restrict__ biasp,
    float* __restrict__ out,
    const int* __restrict__ flags)
{
    const int bbf = flags[2];
    const int slice = blockIdx.x & 7;     // == XCD id under round-robin dispatch
    const int chunk = blockIdx.x >> 3;    // 0..255
    const int wv   = threadIdx.x >> 6;
    const int lane = threadIdx.x & 63;
    const int g = lane >> 3;              // edge group 0..7
    const int u = lane & 7;               // column sub-lane 0..7
    const int co = slice * 64 + u * 8;    // column offset in h/out

    // bias slice (8 floats per lane)
    float b[8];
    if (bbf) {
        const unsigned short* bu = (const unsigned short*)biasp;
        #pragma unroll
        for (int j = 0; j < 8; j++) b[j] = bfr(bu[co + j]);
    } else {
        const float* bf = (const float*)biasp;
        #pragma unroll
        for (int j = 0; j < 8; j++) b[j] = bf[co + j];
    }

    const int RPB = (N_NODES + 2047) / 2048 * 8;  // 196 rows per chunk
    const int r0 = chunk * RPB;
    int r1 = r0 + RPB;
    if (r1 > N_NODES) r1 = N_NODES;

    for (int row = r0 + wv; row < r1; row += 4) {
        int beg = row_ptr[row];
        int end = row_ptr[row + 1];

        float acc[8];
        #pragma unroll
        for (int j = 0; j < 8; j++) acc[j] = 0.0f;

        int e = beg + g;
        for (; e + 8 < end; e += 16) {
            int   s0 = (int)__builtin_nontemporal_load(&csr_src[e]);
            float w0 = __builtin_nontemporal_load(&csr_w[e]);
            int   s1 = (int)__builtin_nontemporal_load(&csr_src[e + 8]);
            float w1 = __builtin_nontemporal_load(&csr_w[e + 8]);
            u16x8 h0 = *(const u16x8*)(h + (long long)s0 * UNITS + co);
            u16x8 h1 = *(const u16x8*)(h + (long long)s1 * UNITS + co);
            #pragma unroll
            for (int j = 0; j < 8; j++) acc[j] += w0 * bfr(h0[j]);
            #pragma unroll
            for (int j = 0; j < 8; j++) acc[j] += w1 * bfr(h1[j]);
        }
        if (e < end) {
            int   s0 = (int)__builtin_nontemporal_load(&csr_src[e]);
            float w0 = __builtin_nontemporal_load(&csr_w[e]);
            u16x8 h0 = *(const u16x8*)(h + (long long)s0 * UNITS + co);
            #pragma unroll
            for (int j = 0; j < 8; j++) acc[j] += w0 * bfr(h0[j]);
        }

        // reduce across the 8 edge-groups (lane bits 3..5)
        #pragma unroll
        for (int m = 8; m < 64; m <<= 1) {
            #pragma unroll
            for (int j = 0; j < 8; j++) acc[j] += __shfl_xor(acc[j], m, 64);
        }

        if (g == 0) {
            f32x4 o0, o1;
            float v;
            v = acc[0] + b[0]; o0.x = v > 0.0f ? v : 0.0f;
            v = acc[1] + b[1]; o0.y = v > 0.0f ? v : 0.0f;
            v = acc[2] + b[2]; o0.z = v > 0.0f ? v : 0.0f;
            v = acc[3] + b[3]; o0.w = v > 0.0f ? v : 0.0f;
            v = acc[4] + b[4]; o1.x = v > 0.0f ? v : 0.0f;
            v = acc[5] + b[5]; o1.y = v > 0.0f ? v : 0.0f;
            v = acc[6] + b[6]; o1.z = v > 0.0f ? v : 0.0f;
            v = acc[7] + b[7]; o1.w = v > 0.0f ? v : 0.0f;
            float* op = out + (long long)row * UNITS + co;
            __builtin_nontemporal_store(o0, (f32x4*)(op + 0));
            __builtin_nontemporal_store(o1, (f32x4*)(op + 4));
        }
    }
}

extern "C" __attribute__((visibility("default")))
void kernel_launch(void* const* d_in, const int* in_sizes, int n_in,
                   void* d_out, int out_size, void* d_ws, size_t ws_size,
                   hipStream_t stream)
{
    const void* X    = d_in[0];
    const void* W    = d_in[1];
    const void* bias = d_in[2];
    const void* ew   = d_in[3];
    const void* esrc = d_in[4];
    const void* edst = d_in[5];
    float* out = (float*)d_out;

    char* ws = (char*)d_ws;
    size_t off = 0;
    unsigned short* h  = (unsigned short*)(ws + off); off += (size_t)N_NODES * UNITS * 2;  // 51.2 MB
    unsigned short* Xb = (unsigned short*)(ws + off); off += (size_t)N_NODES * D_FEAT * 2; // 51.2 MB
    unsigned short* Wt = (unsigned short*)(ws + off); off += (size_t)D_FEAT * UNITS * 2;   // 0.5 MB
    unsigned short* csr_src = (unsigned short*)(ws + off); off += (size_t)N_EDGES * 4;     // u16 used, 4B reserved
    float* csr_w   = (float*)(ws + off); off += (size_t)N_EDGES * 4;                        // 6.4 MB
    int*   counts  = (int*)(ws + off);   off += (size_t)N_NODES * 4;
    int*   row_ptr = (int*)(ws + off);   off += (size_t)(N_NODES + 1) * 4 + 12;
    int*   row_fill= (int*)(ws + off);   off += (size_t)N_NODES * 4;
    int*   flags   = (int*)(ws + off);   off += 64;
    int*   blk_sums= (int*)(ws + off);   off += 256 * 4;
    int*   blk_offs= (int*)(ws + off);   off += 256 * 4;

    const int NB = (N_NODES + 255) / 256;  // 196

    // 0) detect dtypes
    GCN_detect<<<1, 64, 0, stream>>>(X, W, bias, ew, esrc, edst, flags);

    // 1) zero counts
    GCN_zero<<<NB, 256, 0, stream>>>(counts);

    // 2) X -> bf16 (no-op if already bf16); W -> Wt[n][k] bf16
    GCN_xconv<<<4096, 256, 0, stream>>>(X, Xb, flags);
    {
        dim3 grid(D_FEAT / 64, UNITS / 64);
        GCN_wt<<<grid, 256, 0, stream>>>(W, Wt, flags);
    }

    // 3) h = X @ W via MFMA
    {
        dim3 grid(UNITS / 128, (N_NODES + 127) / 128);
        GCN_gemm_mfma<<<grid, 256, 0, stream>>>(X, Xb, Wt, h, flags);
    }

    // 4) histogram of dst
    GCN_hist<<<(N_EDGES + 255) / 256, 256, 0, stream>>>(edst, counts, flags);

    // 5) 3-phase prefix sum -> row_ptr, row_fill
    GCN_scan1<<<NB, 256, 0, stream>>>(counts, row_ptr, blk_sums);
    GCN_scan2<<<1, 256, 0, stream>>>(blk_sums, blk_offs, row_ptr);
    GCN_scan3<<<NB, 256, 0, stream>>>(row_ptr, row_fill, blk_offs);

    // 6) build CSR (u16 src)
    GCN_build<<<(N_EDGES + 255) / 256, 256, 0, stream>>>(esrc, edst, ew, row_fill,
                                                         csr_src, csr_w, flags);

    // 7) aggregate + bias + relu -> out (8 slices x 256 chunks, XCD-pinned)
    GCNConv_86311662780630_kernel<<<2048, 256, 0, stream>>>(
        h, row_ptr, csr_src, csr_w, bias, out, flags);
}

// Round 3
// 671.497 us; speedup vs baseline: 1.2771x; 1.0535x over previous
//
#include <hip/hip_runtime.h>
#include <hip/hip_bf16.h>
#include <stdint.h>

#define N_NODES 50000
#define N_EDGES 1600000
#define D_FEAT  512
#define UNITS   512

// Aggregate pass structure: 4 sequential column stripes of 128 cols.
// Stripe of h = 50000*128*2B = 12.8 MB -> L3-resident between reuses.
#define AGG_PASSES 4
#define AGG_COLS   (UNITS / AGG_PASSES)          // 128
#define AGG_BPP    ((N_NODES + 3) / 4)           // 12500 blocks per pass (4 rows/block)

typedef __attribute__((ext_vector_type(8))) unsigned short u16x8;
typedef __attribute__((ext_vector_type(8))) short s16x8;
typedef __attribute__((ext_vector_type(4))) float f32x4;
typedef __attribute__((ext_vector_type(2))) float f32x2;

static __device__ __forceinline__ float bfr(unsigned short u) {
    union { unsigned int i; float f; } c;
    c.i = ((unsigned int)u) << 16;
    return c.f;
}

static __device__ __forceinline__ unsigned short f2bfr(float f) {
    union { unsigned int i; float f; } c;
    c.f = f;
    unsigned int x = c.i;
    unsigned int rounded = x + 0x7FFF + ((x >> 16) & 1);
    return (unsigned short)(rounded >> 16);
}

// async 16B global -> LDS (width=16 verified on gfx950)
static __device__ __forceinline__ void gload16(const unsigned short* g, unsigned short* l) {
    __builtin_amdgcn_global_load_lds(
        (const __attribute__((address_space(1))) void*)g,
        (__attribute__((address_space(3))) void*)l, 16, 0, 0);
}

// flags: [0]=X bf16, [1]=W bf16, [2]=bias bf16, [3]=ew bf16, [4]=esrc int64, [5]=edst int64
extern "C" __global__ void __launch_bounds__(64) GCN_detect(
    const void* X, const void* W, const void* bias, const void* ew,
    const void* esrc, const void* edst, int* flags)
{
    int t = threadIdx.x;
    const unsigned short uX = ((const unsigned short*)X)[2 * t];
    const unsigned short uW = ((const unsigned short*)W)[2 * t];
    const unsigned short uB = ((const unsigned short*)bias)[2 * t];
    const unsigned short uE = ((const unsigned short*)ew)[2 * t];
    int eX = (uX >> 7) & 0xFF, eW = (uW >> 7) & 0xFF;
    int eB = (uB >> 7) & 0xFF, eE = (uE >> 7) & 0xFF;
    unsigned long long mX = __ballot((uX == 0) || (eX >= 100 && eX <= 140));
    unsigned long long mW = __ballot((uW == 0) || (eW >= 100 && eW <= 140));
    unsigned long long mB = __ballot((uB == 0) || (eB >= 100 && eB <= 140));
    unsigned long long mE = __ballot((uE == 0) || (eE >= 100 && eE <= 140));
    unsigned long long mS = __ballot(((const int*)esrc)[2 * t + 1] == 0);
    unsigned long long mD = __ballot(((const int*)edst)[2 * t + 1] == 0);
    if (t == 0) {
        flags[0] = (__popcll(mX) >= 56) ? 1 : 0;
        flags[1] = (__popcll(mW) >= 56) ? 1 : 0;
        flags[2] = (__popcll(mB) >= 56) ? 1 : 0;
        flags[3] = (__popcll(mE) >= 56) ? 1 : 0;
        flags[4] = (__popcll(mS) >= 56) ? 1 : 0;
        flags[5] = (__popcll(mD) >= 56) ? 1 : 0;
    }
}

// ---------------- zero per-dst counts
extern "C" __global__ void __launch_bounds__(256) GCN_zero(int* __restrict__ counts)
{
    int i = blockIdx.x * 256 + threadIdx.x;
    if (i < N_NODES) counts[i] = 0;
}

// ---------------- convert X -> bf16 (only runs work when X is fp32)
extern "C" __global__ void __launch_bounds__(256) GCN_xconv(
    const void* __restrict__ Xp, unsigned short* __restrict__ Xb,
    const int* __restrict__ flags)
{
    if (flags[0]) return; // already bf16, GEMM reads X directly
    const float4* Xf = (const float4*)Xp;
    const long long NQ = (long long)N_NODES * D_FEAT / 4;
    long long stride = (long long)gridDim.x * 256;
    for (long long q = (long long)blockIdx.x * 256 + threadIdx.x; q < NQ; q += stride) {
        float4 v = Xf[q];
        ushort4 o;
        o.x = f2bfr(v.x); o.y = f2bfr(v.y); o.z = f2bfr(v.z); o.w = f2bfr(v.w);
        *(ushort4*)(Xb + q * 4) = o;
    }
}

// ---------------- Wt[n][k] = bf16(W[k][n])  (512x512, LDS tile transpose)
extern "C" __global__ void __launch_bounds__(256) GCN_wt(
    const void* __restrict__ Wp, unsigned short* __restrict__ Wt,
    const int* __restrict__ flags)
{
    __shared__ unsigned short tile[64][65];
    const int wbf = flags[1];
    int k0 = blockIdx.x * 64, n0 = blockIdx.y * 64;
    int t = threadIdx.x;
    for (int p = 0; p < 16; p++) {
        int idx = p * 256 + t;
        int r = idx >> 6, c = idx & 63;
        unsigned short v;
        if (wbf) {
            v = ((const unsigned short*)Wp)[(long long)(k0 + r) * UNITS + n0 + c];
        } else {
            v = f2bfr(((const float*)Wp)[(long long)(k0 + r) * UNITS + n0 + c]);
        }
        tile[r][c] = v;
    }
    __syncthreads();
    for (int p = 0; p < 16; p++) {
        int idx = p * 256 + t;
        int r = idx >> 6, c = idx & 63;
        Wt[(long long)(n0 + r) * D_FEAT + k0 + c] = tile[c][r];
    }
}

// ---------------- histogram of dst
extern "C" __global__ void __launch_bounds__(256) GCN_hist(
    const void* __restrict__ edstp, int* __restrict__ counts,
    const int* __restrict__ flags)
{
    const int d64 = flags[5];
    int e = blockIdx.x * 256 + threadIdx.x;
    if (e >= N_EDGES) return;
    int dst;
    if (d64) {
        dst = (int)((const long long*)edstp)[e];
    } else {
        dst = ((const int*)edstp)[e];
    }
    atomicAdd(&counts[dst], 1);
}

// ---------------- 3-phase exclusive prefix sum
// scan1: per-block (256-wide) exclusive scan -> row_ptr (chunk-local), block sums
extern "C" __global__ void __launch_bounds__(256) GCN_scan1(
    const int* __restrict__ counts, int* __restrict__ row_ptr,
    int* __restrict__ blk_sums)
{
    __shared__ int ws[4];
    int b = blockIdx.x, tid = threadIdx.x;
    int idx = b * 256 + tid;
    int v = (idx < N_NODES) ? counts[idx] : 0;
    int lane = tid & 63, wv = tid >> 6;
    int x = v;
    #pragma unroll
    for (int off = 1; off < 64; off <<= 1) {
        int y = __shfl_up(x, off, 64);
        if (lane >= off) x += y;
    }
    if (lane == 63) ws[wv] = x;
    __syncthreads();
    int wo = 0;
    for (int w = 0; w < wv; w++) wo += ws[w];
    int incl = x + wo;
    if (idx < N_NODES) row_ptr[idx] = incl - v;  // exclusive, chunk-local
    if (tid == 255) blk_sums[b] = incl;
}

// scan2: single block scans the 196 block sums -> block offsets + total
extern "C" __global__ void __launch_bounds__(256) GCN_scan2(
    const int* __restrict__ blk_sums, int* __restrict__ blk_offs,
    int* __restrict__ row_ptr)
{
    __shared__ int ws[4];
    const int NB = (N_NODES + 255) / 256;  // 196
    int tid = threadIdx.x;
    int v = (tid < NB) ? blk_sums[tid] : 0;
    int lane = tid & 63, wv = tid >> 6;
    int x = v;
    #pragma unroll
    for (int off = 1; off < 64; off <<= 1) {
        int y = __shfl_up(x, off, 64);
        if (lane >= off) x += y;
    }
    if (lane == 63) ws[wv] = x;
    __syncthreads();
    int wo = 0;
    for (int w = 0; w < wv; w++) wo += ws[w];
    int incl = x + wo;
    if (tid < NB) blk_offs[tid] = incl - v;
    if (tid == 255) row_ptr[N_NODES] = incl;  // total edges
}

// scan3: add block offsets, fill row_fill
extern "C" __global__ void __launch_bounds__(256) GCN_scan3(
    int* __restrict__ row_ptr, int* __restrict__ row_fill,
    const int* __restrict__ blk_offs)
{
    int idx = blockIdx.x * 256 + threadIdx.x;
    if (idx < N_NODES) {
        int v = row_ptr[idx] + blk_offs[blockIdx.x];
        row_ptr[idx] = v;
        row_fill[idx] = v;
    }
}

// ---------------- build CSR, packed {src, w-bits} in one 8B record
extern "C" __global__ void __launch_bounds__(256) GCN_build(
    const void* __restrict__ esrcp, const void* __restrict__ edstp,
    const void* __restrict__ ewp, int* __restrict__ row_fill,
    uint2* __restrict__ csr, const int* __restrict__ flags)
{
    const int ewbf = flags[3];
    const int s64 = flags[4];
    const int d64 = flags[5];
    int e = blockIdx.x * 256 + threadIdx.x;
    if (e >= N_EDGES) return;
    int src, dst;
    if (s64) {
        src = (int)((const long long*)esrcp)[e];
    } else {
        src = ((const int*)esrcp)[e];
    }
    if (d64) {
        dst = (int)((const long long*)edstp)[e];
    } else {
        dst = ((const int*)edstp)[e];
    }
    float w;
    if (ewbf) {
        w = bfr(((const unsigned short*)ewp)[e]);
    } else {
        w = ((const float*)ewp)[e];
    }
    int pos = atomicAdd(&row_fill[dst], 1);
    uint2 rec;
    rec.x = (unsigned int)src;
    rec.y = __float_as_uint(w);
    csr[pos] = rec;
}

// ---------------- MFMA GEMM: h[M,N] = X[M,K] @ W[K,N], m97 structure
// 128x128 tile, BK=32, 4 waves (2x2), each wave 4x4 of 16x16x32 bf16 MFMA.
extern "C" __global__ void __launch_bounds__(256) GCN_gemm_mfma(
    const void* __restrict__ Xp, const unsigned short* __restrict__ Xb,
    const unsigned short* __restrict__ Wt,
    unsigned short* __restrict__ Cu, const int* __restrict__ flags)
{
    __shared__ unsigned short As[128 * 32];  // 8 KB, row-major [m][k]
    __shared__ unsigned short Bs[128 * 32];  // 8 KB, row-major [n][k]

    const unsigned short* Xsrc = flags[0] ? (const unsigned short*)Xp : Xb;

    const int tid  = threadIdx.x;
    const int wave = tid >> 6, lane = tid & 63;
    const int quad = lane >> 4, l16 = lane & 15;
    const int wm = wave >> 1, wn = wave & 1;
    const int row0 = blockIdx.y * 128;   // M tile
    const int n0   = blockIdx.x * 128;   // N tile

    f32x4 acc[4][4];
    #pragma unroll
    for (int i = 0; i < 4; i++) {
        #pragma unroll
        for (int j = 0; j < 4; j++) {
            acc[i][j] = (f32x4){0.0f, 0.0f, 0.0f, 0.0f};
        }
    }

    for (int k0 = 0; k0 < D_FEAT; k0 += 32) {
        // stage A (128x32) and B (128x32): 512 x 16B each, 256 threads x 2
        #pragma unroll
        for (int it = 0; it < 2; it++) {
            int flat = it * 256 + tid;          // 0..511
            int r = flat >> 2, cb = flat & 3;   // row, 8-elem chunk
            int gr = row0 + r;
            if (gr > N_NODES - 1) gr = N_NODES - 1;   // clamp (dup loads ok)
            gload16(Xsrc + (long long)gr * D_FEAT + k0 + cb * 8, As + flat * 8);
            gload16(Wt + (long long)(n0 + r) * D_FEAT + k0 + cb * 8, Bs + flat * 8);
        }
        __syncthreads();

        s16x8 a[4], b[4];
        #pragma unroll
        for (int i = 0; i < 4; i++) {
            a[i] = *(const s16x8*)(As + ((wm * 64 + i * 16 + l16) * 32 + quad * 8));
        }
        #pragma unroll
        for (int j = 0; j < 4; j++) {
            b[j] = *(const s16x8*)(Bs + ((wn * 64 + j * 16 + l16) * 32 + quad * 8));
        }
        #pragma unroll
        for (int i = 0; i < 4; i++) {
            #pragma unroll
            for (int j = 0; j < 4; j++) {
                acc[i][j] = __builtin_amdgcn_mfma_f32_16x16x32_bf16(
                    a[i], b[j], acc[i][j], 0, 0, 0);
            }
        }
        __syncthreads();
    }

    // epilogue: C/D layout col=lane&15, row=quad*4+reg (m89-verified)
    #pragma unroll
    for (int i = 0; i < 4; i++) {
        #pragma unroll
        for (int r = 0; r < 4; r++) {
            int gr = row0 + wm * 64 + i * 16 + quad * 4 + r;
            if (gr < N_NODES) {
                #pragma unroll
                for (int j = 0; j < 4; j++) {
                    int gc = n0 + wn * 64 + j * 16 + l16;
                    Cu[(long long)gr * UNITS + gc] = f2bfr(acc[i][j][r]);
                }
            }
        }
    }
}

// ---------------- Aggregate: 4 sequential 128-col passes for L3 residency.
// Wave per row (no cross-lane reduce), lane owns 2 cols (4B gather/lane,
// 256B contiguous per edge). csr record = 8B broadcast load. Unroll x4 with
// dual accumulators for memory-level parallelism. Pass sequencing relies on
// in-order block dispatch: pass = blockIdx.x / AGG_BPP.
extern "C" __global__ void __launch_bounds__(256) GCNConv_86311662780630_kernel(
    const unsigned short* __restrict__ h,
    const int* __restrict__ row_ptr,
    const uint2* __restrict__ csr,
    const void* __restrict__ biasp,
    float* __restrict__ out,
    const int* __restrict__ flags)
{
    const int bbf = flags[2];
    const int bx = blockIdx.x;
    const int pass = bx / AGG_BPP;
    const int rb   = bx - pass * AGG_BPP;
    const int wv   = threadIdx.x >> 6;
    const int lane = threadIdx.x & 63;
    const int row  = rb * 4 + wv;
    if (row >= N_NODES) return;
    const int co = pass * AGG_COLS + lane * 2;

    float b0, b1;
    if (bbf) {
        const unsigned short* bu = (const unsigned short*)biasp;
        b0 = bfr(bu[co]); b1 = bfr(bu[co + 1]);
    } else {
        const float* bf = (const float*)biasp;
        b0 = bf[co]; b1 = bf[co + 1];
    }

    const int beg = row_ptr[row];
    const int end = row_ptr[row + 1];

    float a0 = 0.0f, a1 = 0.0f, c0 = 0.0f, c1 = 0.0f;

    int e = beg;
    for (; e + 3 < end; e += 4) {
        uint2 p0 = csr[e];
        uint2 p1 = csr[e + 1];
        uint2 p2 = csr[e + 2];
        uint2 p3 = csr[e + 3];
        unsigned int h0 = *(const unsigned int*)(h + (size_t)p0.x * UNITS + co);
        unsigned int h1 = *(const unsigned int*)(h + (size_t)p1.x * UNITS + co);
        unsigned int h2 = *(const unsigned int*)(h + (size_t)p2.x * UNITS + co);
        unsigned int h3 = *(const unsigned int*)(h + (size_t)p3.x * UNITS + co);
        float w0 = __uint_as_float(p0.y);
        float w1 = __uint_as_float(p1.y);
        float w2 = __uint_as_float(p2.y);
        float w3 = __uint_as_float(p3.y);
        a0 += w0 * bfr((unsigned short)(h0 & 0xFFFF));
        a1 += w0 * bfr((unsigned short)(h0 >> 16));
        c0 += w1 * bfr((unsigned short)(h1 & 0xFFFF));
        c1 += w1 * bfr((unsigned short)(h1 >> 16));
        a0 += w2 * bfr((unsigned short)(h2 & 0xFFFF));
        a1 += w2 * bfr((unsigned short)(h2 >> 16));
        c0 += w3 * bfr((unsigned short)(h3 & 0xFFFF));
        c1 += w3 * bfr((unsigned short)(h3 >> 16));
    }
    for (; e < end; e++) {
        uint2 p = csr[e];
        unsigned int hv = *(const unsigned int*)(h + (size_t)p.x * UNITS + co);
        float w = __uint_as_float(p.y);
        a0 += w * bfr((unsigned short)(hv & 0xFFFF));
        a1 += w * bfr((unsigned short)(hv >> 16));
    }

    float r0 = a0 + c0 + b0;
    float r1 = a1 + c1 + b1;
    r0 = r0 > 0.0f ? r0 : 0.0f;
    r1 = r1 > 0.0f ? r1 : 0.0f;
    f32x2 o;
    o.x = r0; o.y = r1;
    __builtin_nontemporal_store(o, (f32x2*)(out + (size_t)row * UNITS + co));
}

extern "C" __attribute__((visibility("default")))
void kernel_launch(void* const* d_in, const int* in_sizes, int n_in,
                   void* d_out, int out_size, void* d_ws, size_t ws_size,
                   hipStream_t stream)
{
    const void* X    = d_in[0];
    const void* W    = d_in[1];
    const void* bias = d_in[2];
    const void* ew   = d_in[3];
    const void* esrc = d_in[4];
    const void* edst = d_in[5];
    float* out = (float*)d_out;

    char* ws = (char*)d_ws;
    size_t off = 0;
    unsigned short* h  = (unsigned short*)(ws + off); off += (size_t)N_NODES * UNITS * 2;  // 51.2 MB
    unsigned short* Xb = (unsigned short*)(ws + off); off += (size_t)N_NODES * D_FEAT * 2; // 51.2 MB
    unsigned short* Wt = (unsigned short*)(ws + off); off += (size_t)D_FEAT * UNITS * 2;   // 0.5 MB
    uint2* csr     = (uint2*)(ws + off); off += (size_t)N_EDGES * 8;                        // 12.8 MB
    int*   counts  = (int*)(ws + off);   off += (size_t)N_NODES * 4;
    int*   row_ptr = (int*)(ws + off);   off += (size_t)(N_NODES + 1) * 4 + 12;
    int*   row_fill= (int*)(ws + off);   off += (size_t)N_NODES * 4;
    int*   flags   = (int*)(ws + off);   off += 64;
    int*   blk_sums= (int*)(ws + off);   off += 256 * 4;
    int*   blk_offs= (int*)(ws + off);   off += 256 * 4;

    const int NB = (N_NODES + 255) / 256;  // 196

    // 0) detect dtypes
    GCN_detect<<<1, 64, 0, stream>>>(X, W, bias, ew, esrc, edst, flags);

    // 1) zero counts
    GCN_zero<<<NB, 256, 0, stream>>>(counts);

    // 2) X -> bf16 (no-op if already bf16); W -> Wt[n][k] bf16
    GCN_xconv<<<4096, 256, 0, stream>>>(X, Xb, flags);
    {
        dim3 grid(D_FEAT / 64, UNITS / 64);
        GCN_wt<<<grid, 256, 0, stream>>>(W, Wt, flags);
    }

    // 3) h = X @ W via MFMA
    {
        dim3 grid(UNITS / 128, (N_NODES + 127) / 128);
        GCN_gemm_mfma<<<grid, 256, 0, stream>>>(X, Xb, Wt, h, flags);
    }

    // 4) histogram of dst
    GCN_hist<<<(N_EDGES + 255) / 256, 256, 0, stream>>>(edst, counts, flags);

    // 5) 3-phase prefix sum -> row_ptr, row_fill
    GCN_scan1<<<NB, 256, 0, stream>>>(counts, row_ptr, blk_sums);
    GCN_scan2<<<1, 256, 0, stream>>>(blk_sums, blk_offs, row_ptr);
    GCN_scan3<<<NB, 256, 0, stream>>>(row_ptr, row_fill, blk_offs);

    // 6) build CSR (packed uint2 {src, w})
    GCN_build<<<(N_EDGES + 255) / 256, 256, 0, stream>>>(esrc, edst, ew, row_fill,
                                                         csr, flags);

    // 7) aggregate + bias + relu -> out (4 sequential 128-col passes)
    GCNConv_86311662780630_kernel<<<AGG_PASSES * AGG_BPP, 256, 0, stream>>>(
        h, row_ptr, csr, bias, out, flags);
}

// Round 4
// 655.092 us; speedup vs baseline: 1.3091x; 1.0250x over previous
//
#include <hip/hip_runtime.h>
#include <hip/hip_bf16.h>
#include <stdint.h>

#define N_NODES 50000
#define N_EDGES 1600000
#define D_FEAT  512
#define UNITS   512

typedef __attribute__((ext_vector_type(8))) unsigned short u16x8;
typedef __attribute__((ext_vector_type(8))) short s16x8;
typedef __attribute__((ext_vector_type(4))) float f32x4;

static __device__ __forceinline__ float bfr(unsigned short u) {
    union { unsigned int i; float f; } c;
    c.i = ((unsigned int)u) << 16;
    return c.f;
}

static __device__ __forceinline__ unsigned short f2bfr(float f) {
    union { unsigned int i; float f; } c;
    c.f = f;
    unsigned int x = c.i;
    unsigned int rounded = x + 0x7FFF + ((x >> 16) & 1);
    return (unsigned short)(rounded >> 16);
}

// async 16B global -> LDS (width=16 verified on gfx950)
static __device__ __forceinline__ void gload16(const unsigned short* g, unsigned short* l) {
    __builtin_amdgcn_global_load_lds(
        (const __attribute__((address_space(1))) void*)g,
        (__attribute__((address_space(3))) void*)l, 16, 0, 0);
}

// flags: [0]=X bf16, [1]=W bf16, [2]=bias bf16, [3]=ew bf16, [4]=esrc int64, [5]=edst int64
extern "C" __global__ void __launch_bounds__(64) GCN_detect(
    const void* X, const void* W, const void* bias, const void* ew,
    const void* esrc, const void* edst, int* flags)
{
    int t = threadIdx.x;
    const unsigned short uX = ((const unsigned short*)X)[2 * t];
    const unsigned short uW = ((const unsigned short*)W)[2 * t];
    const unsigned short uB = ((const unsigned short*)bias)[2 * t];
    const unsigned short uE = ((const unsigned short*)ew)[2 * t];
    int eX = (uX >> 7) & 0xFF, eW = (uW >> 7) & 0xFF;
    int eB = (uB >> 7) & 0xFF, eE = (uE >> 7) & 0xFF;
    unsigned long long mX = __ballot((uX == 0) || (eX >= 100 && eX <= 140));
    unsigned long long mW = __ballot((uW == 0) || (eW >= 100 && eW <= 140));
    unsigned long long mB = __ballot((uB == 0) || (eB >= 100 && eB <= 140));
    unsigned long long mE = __ballot((uE == 0) || (eE >= 100 && eE <= 140));
    unsigned long long mS = __ballot(((const int*)esrc)[2 * t + 1] == 0);
    unsigned long long mD = __ballot(((const int*)edst)[2 * t + 1] == 0);
    if (t == 0) {
        flags[0] = (__popcll(mX) >= 56) ? 1 : 0;
        flags[1] = (__popcll(mW) >= 56) ? 1 : 0;
        flags[2] = (__popcll(mB) >= 56) ? 1 : 0;
        flags[3] = (__popcll(mE) >= 56) ? 1 : 0;
        flags[4] = (__popcll(mS) >= 56) ? 1 : 0;
        flags[5] = (__popcll(mD) >= 56) ? 1 : 0;
    }
}

// ---------------- zero per-dst counts
extern "C" __global__ void __launch_bounds__(256) GCN_zero(int* __restrict__ counts)
{
    int i = blockIdx.x * 256 + threadIdx.x;
    if (i < N_NODES) counts[i] = 0;
}

// ---------------- convert X -> bf16 (only runs work when X is fp32)
extern "C" __global__ void __launch_bounds__(256) GCN_xconv(
    const void* __restrict__ Xp, unsigned short* __restrict__ Xb,
    const int* __restrict__ flags)
{
    if (flags[0]) return; // already bf16, GEMM reads X directly
    const float4* Xf = (const float4*)Xp;
    const long long NQ = (long long)N_NODES * D_FEAT / 4;
    long long stride = (long long)gridDim.x * 256;
    for (long long q = (long long)blockIdx.x * 256 + threadIdx.x; q < NQ; q += stride) {
        float4 v = Xf[q];
        ushort4 o;
        o.x = f2bfr(v.x); o.y = f2bfr(v.y); o.z = f2bfr(v.z); o.w = f2bfr(v.w);
        *(ushort4*)(Xb + q * 4) = o;
    }
}

// ---------------- Wt[n][k] = bf16(W[k][n])  (512x512, LDS tile transpose)
extern "C" __global__ void __launch_bounds__(256) GCN_wt(
    const void* __restrict__ Wp, unsigned short* __restrict__ Wt,
    const int* __restrict__ flags)
{
    __shared__ unsigned short tile[64][65];
    const int wbf = flags[1];
    int k0 = blockIdx.x * 64, n0 = blockIdx.y * 64;
    int t = threadIdx.x;
    for (int p = 0; p < 16; p++) {
        int idx = p * 256 + t;
        int r = idx >> 6, c = idx & 63;
        unsigned short v;
        if (wbf) {
            v = ((const unsigned short*)Wp)[(long long)(k0 + r) * UNITS + n0 + c];
        } else {
            v = f2bfr(((const float*)Wp)[(long long)(k0 + r) * UNITS + n0 + c]);
        }
        tile[r][c] = v;
    }
    __syncthreads();
    for (int p = 0; p < 16; p++) {
        int idx = p * 256 + t;
        int r = idx >> 6, c = idx & 63;
        Wt[(long long)(n0 + r) * D_FEAT + k0 + c] = tile[c][r];
    }
}

// ---------------- histogram of dst
extern "C" __global__ void __launch_bounds__(256) GCN_hist(
    const void* __restrict__ edstp, int* __restrict__ counts,
    const int* __restrict__ flags)
{
    const int d64 = flags[5];
    int e = blockIdx.x * 256 + threadIdx.x;
    if (e >= N_EDGES) return;
    int dst;
    if (d64) {
        dst = (int)((const long long*)edstp)[e];
    } else {
        dst = ((const int*)edstp)[e];
    }
    atomicAdd(&counts[dst], 1);
}

// ---------------- 3-phase exclusive prefix sum
// scan1: per-block (256-wide) exclusive scan -> row_ptr (chunk-local), block sums
extern "C" __global__ void __launch_bounds__(256) GCN_scan1(
    const int* __restrict__ counts, int* __restrict__ row_ptr,
    int* __restrict__ blk_sums)
{
    __shared__ int ws[4];
    int b = blockIdx.x, tid = threadIdx.x;
    int idx = b * 256 + tid;
    int v = (idx < N_NODES) ? counts[idx] : 0;
    int lane = tid & 63, wv = tid >> 6;
    int x = v;
    #pragma unroll
    for (int off = 1; off < 64; off <<= 1) {
        int y = __shfl_up(x, off, 64);
        if (lane >= off) x += y;
    }
    if (lane == 63) ws[wv] = x;
    __syncthreads();
    int wo = 0;
    for (int w = 0; w < wv; w++) wo += ws[w];
    int incl = x + wo;
    if (idx < N_NODES) row_ptr[idx] = incl - v;  // exclusive, chunk-local
    if (tid == 255) blk_sums[b] = incl;
}

// scan2: single block scans the 196 block sums -> block offsets + total
extern "C" __global__ void __launch_bounds__(256) GCN_scan2(
    const int* __restrict__ blk_sums, int* __restrict__ blk_offs,
    int* __restrict__ row_ptr)
{
    __shared__ int ws[4];
    const int NB = (N_NODES + 255) / 256;  // 196
    int tid = threadIdx.x;
    int v = (tid < NB) ? blk_sums[tid] : 0;
    int lane = tid & 63, wv = tid >> 6;
    int x = v;
    #pragma unroll
    for (int off = 1; off < 64; off <<= 1) {
        int y = __shfl_up(x, off, 64);
        if (lane >= off) x += y;
    }
    if (lane == 63) ws[wv] = x;
    __syncthreads();
    int wo = 0;
    for (int w = 0; w < wv; w++) wo += ws[w];
    int incl = x + wo;
    if (tid < NB) blk_offs[tid] = incl - v;
    if (tid == 255) row_ptr[N_NODES] = incl;  // total edges
}

// scan3: add block offsets, fill row_fill
extern "C" __global__ void __launch_bounds__(256) GCN_scan3(
    int* __restrict__ row_ptr, int* __restrict__ row_fill,
    const int* __restrict__ blk_offs)
{
    int idx = blockIdx.x * 256 + threadIdx.x;
    if (idx < N_NODES) {
        int v = row_ptr[idx] + blk_offs[blockIdx.x];
        row_ptr[idx] = v;
        row_fill[idx] = v;
    }
}

// ---------------- build CSR, packed {src, w-bits} in one 8B record
extern "C" __global__ void __launch_bounds__(256) GCN_build(
    const void* __restrict__ esrcp, const void* __restrict__ edstp,
    const void* __restrict__ ewp, int* __restrict__ row_fill,
    uint2* __restrict__ csr, const int* __restrict__ flags)
{
    const int ewbf = flags[3];
    const int s64 = flags[4];
    const int d64 = flags[5];
    int e = blockIdx.x * 256 + threadIdx.x;
    if (e >= N_EDGES) return;
    int src, dst;
    if (s64) {
        src = (int)((const long long*)esrcp)[e];
    } else {
        src = ((const int*)esrcp)[e];
    }
    if (d64) {
        dst = (int)((const long long*)edstp)[e];
    } else {
        dst = ((const int*)edstp)[e];
    }
    float w;
    if (ewbf) {
        w = bfr(((const unsigned short*)ewp)[e]);
    } else {
        w = ((const float*)ewp)[e];
    }
    int pos = atomicAdd(&row_fill[dst], 1);
    uint2 rec;
    rec.x = (unsigned int)src;
    rec.y = __float_as_uint(w);
    csr[pos] = rec;
}

// ---------------- MFMA GEMM: h[M,N] = X[M,K] @ W[K,N], m97 structure
// 128x128 tile, BK=32, 4 waves (2x2), each wave 4x4 of 16x16x32 bf16 MFMA.
extern "C" __global__ void __launch_bounds__(256) GCN_gemm_mfma(
    const void* __restrict__ Xp, const unsigned short* __restrict__ Xb,
    const unsigned short* __restrict__ Wt,
    unsigned short* __restrict__ Cu, const int* __restrict__ flags)
{
    __shared__ unsigned short As[128 * 32];  // 8 KB, row-major [m][k]
    __shared__ unsigned short Bs[128 * 32];  // 8 KB, row-major [n][k]

    const unsigned short* Xsrc = flags[0] ? (const unsigned short*)Xp : Xb;

    const int tid  = threadIdx.x;
    const int wave = tid >> 6, lane = tid & 63;
    const int quad = lane >> 4, l16 = lane & 15;
    const int wm = wave >> 1, wn = wave & 1;
    const int row0 = blockIdx.y * 128;   // M tile
    const int n0   = blockIdx.x * 128;   // N tile

    f32x4 acc[4][4];
    #pragma unroll
    for (int i = 0; i < 4; i++) {
        #pragma unroll
        for (int j = 0; j < 4; j++) {
            acc[i][j] = (f32x4){0.0f, 0.0f, 0.0f, 0.0f};
        }
    }

    for (int k0 = 0; k0 < D_FEAT; k0 += 32) {
        // stage A (128x32) and B (128x32): 512 x 16B each, 256 threads x 2
        #pragma unroll
        for (int it = 0; it < 2; it++) {
            int flat = it * 256 + tid;          // 0..511
            int r = flat >> 2, cb = flat & 3;   // row, 8-elem chunk
            int gr = row0 + r;
            if (gr > N_NODES - 1) gr = N_NODES - 1;   // clamp (dup loads ok)
            gload16(Xsrc + (long long)gr * D_FEAT + k0 + cb * 8, As + flat * 8);
            gload16(Wt + (long long)(n0 + r) * D_FEAT + k0 + cb * 8, Bs + flat * 8);
        }
        __syncthreads();

        s16x8 a[4], b[4];
        #pragma unroll
        for (int i = 0; i < 4; i++) {
            a[i] = *(const s16x8*)(As + ((wm * 64 + i * 16 + l16) * 32 + quad * 8));
        }
        #pragma unroll
        for (int j = 0; j < 4; j++) {
            b[j] = *(const s16x8*)(Bs + ((wn * 64 + j * 16 + l16) * 32 + quad * 8));
        }
        #pragma unroll
        for (int i = 0; i < 4; i++) {
            #pragma unroll
            for (int j = 0; j < 4; j++) {
                acc[i][j] = __builtin_amdgcn_mfma_f32_16x16x32_bf16(
                    a[i], b[j], acc[i][j], 0, 0, 0);
            }
        }
        __syncthreads();
    }

    // epilogue: C/D layout col=lane&15, row=quad*4+reg (m89-verified)
    #pragma unroll
    for (int i = 0; i < 4; i++) {
        #pragma unroll
        for (int r = 0; r < 4; r++) {
            int gr = row0 + wm * 64 + i * 16 + quad * 4 + r;
            if (gr < N_NODES) {
                #pragma unroll
                for (int j = 0; j < 4; j++) {
                    int gc = n0 + wn * 64 + j * 16 + l16;
                    Cu[(long long)gr * UNITS + gc] = f2bfr(acc[i][j][r]);
                }
            }
        }
    }
}

// ---------------- Aggregate: wave-per-row, full 512 cols, 16B/lane per edge.
// Single edge-visit per edge (minimal instruction overhead per gathered byte).
// Packed uint2 csr record = one 8B broadcast load per edge. Unroll 4 with two
// independent accumulator banks: 4 KB of gather payload in flight per wave to
// cover L2/L3 gather latency.
extern "C" __global__ void __launch_bounds__(256) GCNConv_86311662780630_kernel(
    const unsigned short* __restrict__ h,
    const int* __restrict__ row_ptr,
    const uint2* __restrict__ csr,
    const void* __restrict__ biasp,
    float* __restrict__ out,
    const int* __restrict__ flags)
{
    const int bbf = flags[2];
    const int wv = threadIdx.x >> 6;
    const int lane = threadIdx.x & 63;
    const int row = blockIdx.x * 4 + wv;
    if (row >= N_NODES) return;
    const int fo = lane * 8;

    const int beg = row_ptr[row];
    const int end = row_ptr[row + 1];

    float acc0[8], acc1[8];
    #pragma unroll
    for (int j = 0; j < 8; j++) { acc0[j] = 0.0f; acc1[j] = 0.0f; }

    const unsigned short* hp = h + fo;

    int e = beg;
    for (; e + 3 < end; e += 4) {
        uint2 p0 = csr[e];
        uint2 p1 = csr[e + 1];
        uint2 p2 = csr[e + 2];
        uint2 p3 = csr[e + 3];
        u16x8 h0 = *(const u16x8*)(hp + (size_t)p0.x * UNITS);
        u16x8 h1 = *(const u16x8*)(hp + (size_t)p1.x * UNITS);
        u16x8 h2 = *(const u16x8*)(hp + (size_t)p2.x * UNITS);
        u16x8 h3 = *(const u16x8*)(hp + (size_t)p3.x * UNITS);
        float w0 = __uint_as_float(p0.y);
        float w1 = __uint_as_float(p1.y);
        float w2 = __uint_as_float(p2.y);
        float w3 = __uint_as_float(p3.y);
        #pragma unroll
        for (int j = 0; j < 8; j++) acc0[j] += w0 * bfr(h0[j]);
        #pragma unroll
        for (int j = 0; j < 8; j++) acc1[j] += w1 * bfr(h1[j]);
        #pragma unroll
        for (int j = 0; j < 8; j++) acc0[j] += w2 * bfr(h2[j]);
        #pragma unroll
        for (int j = 0; j < 8; j++) acc1[j] += w3 * bfr(h3[j]);
    }
    for (; e < end; e++) {
        uint2 p = csr[e];
        u16x8 h0 = *(const u16x8*)(hp + (size_t)p.x * UNITS);
        float w = __uint_as_float(p.y);
        #pragma unroll
        for (int j = 0; j < 8; j++) acc0[j] += w * bfr(h0[j]);
    }

    float b[8];
    if (bbf) {
        const unsigned short* bu = (const unsigned short*)biasp;
        #pragma unroll
        for (int j = 0; j < 8; j++) b[j] = bfr(bu[fo + j]);
    } else {
        const float* bf = (const float*)biasp;
        #pragma unroll
        for (int j = 0; j < 8; j++) b[j] = bf[fo + j];
    }

    f32x4 o0, o1;
    float v;
    v = acc0[0] + acc1[0] + b[0]; o0.x = v > 0.0f ? v : 0.0f;
    v = acc0[1] + acc1[1] + b[1]; o0.y = v > 0.0f ? v : 0.0f;
    v = acc0[2] + acc1[2] + b[2]; o0.z = v > 0.0f ? v : 0.0f;
    v = acc0[3] + acc1[3] + b[3]; o0.w = v > 0.0f ? v : 0.0f;
    v = acc0[4] + acc1[4] + b[4]; o1.x = v > 0.0f ? v : 0.0f;
    v = acc0[5] + acc1[5] + b[5]; o1.y = v > 0.0f ? v : 0.0f;
    v = acc0[6] + acc1[6] + b[6]; o1.z = v > 0.0f ? v : 0.0f;
    v = acc0[7] + acc1[7] + b[7]; o1.w = v > 0.0f ? v : 0.0f;
    float* op = out + (size_t)row * UNITS + fo;
    __builtin_nontemporal_store(o0, (f32x4*)(op + 0));
    __builtin_nontemporal_store(o1, (f32x4*)(op + 4));
}

extern "C" __attribute__((visibility("default")))
void kernel_launch(void* const* d_in, const int* in_sizes, int n_in,
                   void* d_out, int out_size, void* d_ws, size_t ws_size,
                   hipStream_t stream)
{
    const void* X    = d_in[0];
    const void* W    = d_in[1];
    const void* bias = d_in[2];
    const void* ew   = d_in[3];
    const void* esrc = d_in[4];
    const void* edst = d_in[5];
    float* out = (float*)d_out;

    char* ws = (char*)d_ws;
    size_t off = 0;
    unsigned short* h  = (unsigned short*)(ws + off); off += (size_t)N_NODES * UNITS * 2;  // 51.2 MB
    unsigned short* Xb = (unsigned short*)(ws + off); off += (size_t)N_NODES * D_FEAT * 2; // 51.2 MB
    unsigned short* Wt = (unsigned short*)(ws + off); off += (size_t)D_FEAT * UNITS * 2;   // 0.5 MB
    uint2* csr     = (uint2*)(ws + off); off += (size_t)N_EDGES * 8;                        // 12.8 MB
    int*   counts  = (int*)(ws + off);   off += (size_t)N_NODES * 4;
    int*   row_ptr = (int*)(ws + off);   off += (size_t)(N_NODES + 1) * 4 + 12;
    int*   row_fill= (int*)(ws + off);   off += (size_t)N_NODES * 4;
    int*   flags   = (int*)(ws + off);   off += 64;
    int*   blk_sums= (int*)(ws + off);   off += 256 * 4;
    int*   blk_offs= (int*)(ws + off);   off += 256 * 4;

    const int NB = (N_NODES + 255) / 256;  // 196

    // 0) detect dtypes
    GCN_detect<<<1, 64, 0, stream>>>(X, W, bias, ew, esrc, edst, flags);

    // 1) zero counts
    GCN_zero<<<NB, 256, 0, stream>>>(counts);

    // 2) X -> bf16 (no-op if already bf16); W -> Wt[n][k] bf16
    GCN_xconv<<<4096, 256, 0, stream>>>(X, Xb, flags);
    {
        dim3 grid(D_FEAT / 64, UNITS / 64);
        GCN_wt<<<grid, 256, 0, stream>>>(W, Wt, flags);
    }

    // 3) h = X @ W via MFMA
    {
        dim3 grid(UNITS / 128, (N_NODES + 127) / 128);
        GCN_gemm_mfma<<<grid, 256, 0, stream>>>(X, Xb, Wt, h, flags);
    }

    // 4) histogram of dst
    GCN_hist<<<(N_EDGES + 255) / 256, 256, 0, stream>>>(edst, counts, flags);

    // 5) 3-phase prefix sum -> row_ptr, row_fill
    GCN_scan1<<<NB, 256, 0, stream>>>(counts, row_ptr, blk_sums);
    GCN_scan2<<<1, 256, 0, stream>>>(blk_sums, blk_offs, row_ptr);
    GCN_scan3<<<NB, 256, 0, stream>>>(row_ptr, row_fill, blk_offs);

    // 6) build CSR (packed uint2 {src, w})
    GCN_build<<<(N_EDGES + 255) / 256, 256, 0, stream>>>(esrc, edst, ew, row_fill,
                                                         csr, flags);

    // 7) aggregate + bias + relu -> out (single pass, full width)
    GCNConv_86311662780630_kernel<<<(N_NODES + 3) / 4, 256, 0, stream>>>(
        h, row_ptr, csr, bias, out, flags);
}